// Round 19
// baseline (4318.002 us; speedup 1.0000x reference)
//
#include <hip/hip_runtime.h>
#include <math.h>

typedef _Float16 f16;
typedef f16 f16x8 __attribute__((ext_vector_type(8)));
typedef f16 f16v2 __attribute__((ext_vector_type(2)));
typedef float f32x4 __attribute__((ext_vector_type(4)));

#define NB 64
#define NG 512
#define ND 384
#define NH 6
#define NL 12
#define NDH 64
#define BG (NB * NG)     // 32768
#define BGD (BG * ND)    // 12582912

// ---- scratch layout inside attn_mask region of d_out (float offsets) ----
#define OFF_WQKV   0          // f16[12*1152*384]
#define OFF_WPROJ  2654208
#define OFF_WFC1   3538944
#define OFF_WFC2   7077888
#define OFF_FLAGS  10616832
#define OFF_NKM    10625024
#define OFF_MMAX   10625216
#define OFF_POS    10625280   // f16[12,582,912] (6,291,456 floats)
#define OFF_HID    23208192   // f16[4,194,304]
#define OFF_Y      25305344   // f16[12,582,912]
#define OFF_YBIG   31596800   // f16[50,331,648]
#define OFF_QB     56762624   // f16[12,582,912]
#define OFF_KB     63054080
#define OFF_VT     69345536
#define OFF_OB     75636992
#define OFF_W2T    81928448   // f16[384*128]
#define OFF_HB     81953024   // f16[12,582,912] -> ends 88,244,480

// ---------------------------------------------------------------------------
// async global->LDS 16B
// ---------------------------------------------------------------------------
typedef __attribute__((address_space(3))) void lds_t;
typedef const __attribute__((address_space(1))) void gmem_t;
__device__ __forceinline__ void gload16(const void* g, void* l)
{
    __builtin_amdgcn_global_load_lds((gmem_t*)g, (lds_t*)l, 16, 0, 0);
}

// ---------------------------------------------------------------------------
// Weight transpose + fp32 -> fp16:  src [L][K][N] -> dst [L][N][K]
// ---------------------------------------------------------------------------
__global__ __launch_bounds__(256)
void transpose_kernel(const float* __restrict__ src, f16* __restrict__ dst,
                      int K, int N)
{
    __shared__ float tile[32][33];
    const int l = blockIdx.z;
    const float* S = src + (size_t)l * K * N;
    f16* D = dst + (size_t)l * K * N;
    const int n0 = blockIdx.x * 32, k0 = blockIdx.y * 32;
    const int tx = threadIdx.x, ty = threadIdx.y;
#pragma unroll
    for (int i = 0; i < 32; i += 8)
        tile[ty + i][tx] = S[(size_t)(k0 + ty + i) * N + n0 + tx];
    __syncthreads();
#pragma unroll
    for (int i = 0; i < 32; i += 8)
        D[(size_t)(n0 + ty + i) * K + k0 + tx] = (f16)tile[tx][ty + i];
}

// ---------------------------------------------------------------------------
// Positional MLP stage A (proven-dumb)
// ---------------------------------------------------------------------------
__global__ __launch_bounds__(256)
void dpos_a(const float* cen, const float* w1, const float* b1, f16* hid)
{
    const int idx = blockIdx.x * 256 + threadIdx.x;
    if (idx >= BG * 128) return;
    const int t = idx >> 7, k = idx & 127;
    const int g = t & (NG - 1);
    if (g == 0) { hid[idx] = (f16)0.f; return; }
    const float* c = cen + (size_t)(t - 1) * 3;
    const float hv = c[0] * w1[k] + c[1] * w1[128 + k] + c[2] * w1[256 + k] + b1[k];
    hid[idx] = (f16)(0.5f * hv * (1.0f + erff(hv * 0.70710678118654752f)));
}

__global__ __launch_bounds__(384)
void pos_fix(f16* pos)
{
    const int b = blockIdx.x;
    pos[((size_t)b * NG) * ND + threadIdx.x] = (f16)1.0f;
}

// ---------------------------------------------------------------------------
// Mask pipeline (proven-dumb)
// ---------------------------------------------------------------------------
__global__ __launch_bounds__(512)
void dmask_a(const float* cen, float* pad_out, int* nkm)
{
    const int b = blockIdx.x, j = threadIdx.x;
    const float* c = cen + ((size_t)b * NG + j) * 3;
    const bool pad = (c[0] == -1.f) && (c[1] == -1.f) && (c[2] == -1.f);
    pad_out[b * NG + j] = pad ? 1.f : 0.f;
    if (j == 0) {
        int cnt = 0;
        for (int i = 0; i < NG; i++) {
            const float* ci = cen + ((size_t)b * NG + i) * 3;
            cnt += (ci[0] == -1.f && ci[1] == -1.f && ci[2] == -1.f) ? 1 : 0;
        }
        const int n = NG - cnt;
        const int k = (int)((float)n * 0.1f);
        const int m = (int)((float)(n - k) * 0.6f);
        nkm[b * 3] = n; nkm[b * 3 + 1] = k; nkm[b * 3 + 2] = m;
    }
}

__global__ void dmask_m(const int* nkm, int* Mmax)
{
    if (threadIdx.x == 0 && blockIdx.x == 0) {
        int M = 0;
        for (int b = 0; b < NB; b++) M = max(M, nkm[b * 3 + 2]);
        *Mmax = M;
    }
}

__global__ __launch_bounds__(512)
void dmask_b(const float* cen, const float* noi, const int* nkm,
             const int* Mmax, unsigned char* flags)
{
    const int b = blockIdx.x, j = threadIdx.x;
    const int n = nkm[b * 3], k = nkm[b * 3 + 1], m = nkm[b * 3 + 2];
    const int M = *Mmax;
    const float nz = noi[b * NG + j];
    const bool inreg = (j >= k) && (j < n);
    bool shuf = false;
    if (inreg) {
        int cnt = 0;
        for (int i = 0; i < NG; i++) {
            if (i < k || i >= n) continue;
            const float ui = noi[b * NG + i];
            cnt += (ui < nz) || (ui == nz && i < j);
        }
        shuf = cnt < m;
    }
    const float* c = cen + ((size_t)b * NG + j) * 3;
    const bool pad = (c[0] == -1.f) && (c[1] == -1.f) && (c[2] == -1.f);
    const bool tail = (j >= n) && (j < n + M - m);
    flags[b * NG + j] = (unsigned char)(((shuf | tail) ? 1 : 0) | (pad ? 2 : 0));
}

// ---------------------------------------------------------------------------
// attn_mask emission. Direct (flags in d_ws) + legacy fallback.
// ---------------------------------------------------------------------------
__global__ __launch_bounds__(512)
void mask_out_direct(const unsigned char* __restrict__ flags, float* __restrict__ mo)
{
    const int bq = blockIdx.x;
    const int b = bq >> 9, q = bq & (NG - 1);
    const int j = threadIdx.x;
    const unsigned char f = flags[b * NG + j];
    const float val = ((q < j) || ((f & 1) && (q != j))) ? 1.0f : 0.0f;
#pragma unroll
    for (int h = 0; h < NH; h++)
        mo[(((size_t)(b * NH + h) * NG + q) * NG) + j] = val;
}

__global__ __launch_bounds__(512)
void flags_rep_kernel(const unsigned char* flags, float* mo)
{
    const int bq = blockIdx.x;
    const int b = bq >> 9, q = bq & (NG - 1);
    const int j = threadIdx.x;
    mo[(((size_t)(b * NH) * NG + q) * NG) + j] = (float)flags[b * NG + j];
}

__global__ __launch_bounds__(512)
void mask_out_kernel(float* mo)
{
    const int bq = blockIdx.x;
    const int b = bq >> 9, q = bq & (NG - 1);
    const int j = threadIdx.x;
    const unsigned char f =
        (unsigned char)mo[(((size_t)(b * NH) * NG + q) * NG) + j];
    const float val = ((q < j) || ((f & 1) && (q != j))) ? 1.0f : 0.0f;
#pragma unroll
    for (int h = 0; h < NH; h++)
        mo[(((size_t)(b * NH + h) * NG + q) * NG) + j] = val;
}

// ---------------------------------------------------------------------------
// h0 init: shift-right + start token + pos-add (layer-0 fusion), f16 out
// ---------------------------------------------------------------------------
__global__ __launch_bounds__(256)
void h0_kernel(const float* x, const f16* pos, f16* h)
{
    const size_t i = (size_t)blockIdx.x * 256 + threadIdx.x;
    const int g = (int)((i / ND) & (NG - 1));
    const float xv = x[(g == 0) ? i : (i - ND)];
    const float base = (g == 0) ? 1.0f : xv;
    h[i] = (f16)(base + (float)pos[i]);
}

// ---------------------------------------------------------------------------
// LayerNorm standalone (pre-loop LN1 only). MODE 1: LN -> f16 Y.
// ---------------------------------------------------------------------------
template<int MODE>
__global__ __launch_bounds__(256)
void lnb_kernel(const f16* __restrict__ h,
                const float* __restrict__ w, const float* __restrict__ bb,
                f16* __restrict__ y16, float* __restrict__ y32)
{
    __shared__ float red[4][64];
    const int wid = threadIdx.x >> 6;
    const int lane = threadIdx.x & 63;
    const int t = blockIdx.x * 4 + wid;
    const size_t base = (size_t)t * ND + lane;
    float v[6];
    float s = 0.f;
#pragma unroll
    for (int i = 0; i < 6; i++) {
        const float xv = (float)h[base + i * 64];
        v[i] = xv; s += xv;
    }
    red[wid][lane] = s;
    __syncthreads();
    for (int st = 32; st > 0; st >>= 1) {
        if (lane < st) red[wid][lane] += red[wid][lane + st];
        __syncthreads();
    }
    const float mu = red[wid][0] * (1.f / ND);
    float vs = 0.f;
#pragma unroll
    for (int i = 0; i < 6; i++) { const float d = v[i] - mu; vs += d * d; }
    __syncthreads();
    red[wid][lane] = vs;
    __syncthreads();
    for (int st = 32; st > 0; st >>= 1) {
        if (lane < st) red[wid][lane] += red[wid][lane + st];
        __syncthreads();
    }
    const float rstd = rsqrtf(red[wid][0] * (1.f / ND) + 1e-5f);
#pragma unroll
    for (int i = 0; i < 6; i++) {
        const float o = (v[i] - mu) * rstd * w[lane + i * 64] + bb[lane + i * 64];
        if constexpr (MODE == 2) y32[base + i * 64] = o;
        else                     y16[base + i * 64] = (f16)o;
    }
}

// ---------------------------------------------------------------------------
// MFMA GEMM (proven green). MODE 0: QKV scatter (V tiles: LDS-bounce
// transposed coalesced write). MODE 1: hres(f16) += C. MODE 2: gelu->f16.
// MODE 3: plain C->f16.
// ---------------------------------------------------------------------------
template<int MODE>
__global__ __launch_bounds__(256)
void gemm_kernel(const f16* __restrict__ A, const f16* __restrict__ Bt,
                 const float* __restrict__ bias, int K, int NT,
                 f16* __restrict__ hres, f16* __restrict__ out16,
                 f16* __restrict__ Qo, f16* __restrict__ Ko, f16* __restrict__ Vo)
{
    __shared__ f16 sA[128 * 64];
    __shared__ f16 sB[128 * 64];
    const int tid = threadIdx.x;
    const int w = tid >> 6, lane = tid & 63;
    const int lr = lane & 15, lg = lane >> 4;
    const int wm = w >> 1, wn = w & 1;
    const int N = NT * 128;

    const int nwg = gridDim.x;
    const int chunk = nwg >> 3;
    const int flat = (blockIdx.x & 7) * chunk + (blockIdx.x >> 3);
    const int m0 = (flat / NT) * 128;
    const int n0 = (flat % NT) * 128;

    f32x4 acc[4][4];
#pragma unroll
    for (int mf = 0; mf < 4; mf++)
#pragma unroll
        for (int nf = 0; nf < 4; nf++)
            acc[mf][nf] = (f32x4){0.f, 0.f, 0.f, 0.f};

    const int srow0 = w * 8 + (lane >> 3);
    const int scolB = (lane & 7) * 16;

    for (int k0 = 0; k0 < K; k0 += 64) {
        __syncthreads();
#pragma unroll
        for (int i = 0; i < 4; i++) {
            const int row = i * 32 + srow0;
            const int colB = scolB ^ ((row & 7) << 4);
            const char* ga = (const char*)(A + (size_t)(m0 + row) * K + k0) + colB;
            const char* gb = (const char*)(Bt + (size_t)(n0 + row) * K + k0) + colB;
            gload16(ga, (char*)sA + row * 128 + scolB);
            gload16(gb, (char*)sB + row * 128 + scolB);
        }
        __syncthreads();
#pragma unroll
        for (int kk = 0; kk < 64; kk += 32) {
            f16x8 af[4], bf[4];
#pragma unroll
            for (int mf = 0; mf < 4; mf++) {
                const int r = wm * 64 + mf * 16 + lr;
                const int cb = ((kk + lg * 8) * 2) ^ ((r & 7) << 4);
                af[mf] = *(const f16x8*)((const char*)sA + r * 128 + cb);
            }
#pragma unroll
            for (int nf = 0; nf < 4; nf++) {
                const int r = wn * 64 + nf * 16 + lr;
                const int cb = ((kk + lg * 8) * 2) ^ ((r & 7) << 4);
                bf[nf] = *(const f16x8*)((const char*)sB + r * 128 + cb);
            }
#pragma unroll
            for (int mf = 0; mf < 4; mf++)
#pragma unroll
                for (int nf = 0; nf < 4; nf++)
                    acc[mf][nf] = __builtin_amdgcn_mfma_f32_16x16x32_f16(
                        af[mf], bf[nf], acc[mf][nf], 0, 0, 0);
        }
    }

    if constexpr (MODE == 0) {
        if (n0 >= 768) {
            // V tile: transpose through (now dead) sA/sB, then coalesced write.
            __syncthreads();
#pragma unroll
            for (int mf = 0; mf < 4; mf++) {
#pragma unroll
                for (int nf = 0; nf < 4; nf++) {
                    const int n_local = wn * 64 + nf * 16 + lr;
                    const float bv = bias[n0 + n_local];
                    f16* dst = (wn == 0 ? sA : sB)
                               + (n_local & 63) * 128 + wm * 64 + mf * 16 + lg * 4;
#pragma unroll
                    for (int r = 0; r < 4; r++)
                        dst[r] = (f16)(acc[mf][nf][r] + bv);
                }
            }
            __syncthreads();
            const int row = tid >> 1;
            const int seg = (tid & 1) * 64;
            const int rem = (n0 - 768) + row;
            const int hh = rem >> 6, dh = rem & 63;
            const int bb2 = m0 >> 9;
            const int gg0 = m0 & (NG - 1);
            const f16* src = (row < 64 ? sA : sB) + (row & 63) * 128 + seg;
            f16* dstg = Vo + ((size_t)(bb2 * NH + hh) * NDH + dh) * NG + gg0 + seg;
#pragma unroll
            for (int i = 0; i < 8; i++)
                *(f16x8*)(dstg + i * 8) = *(const f16x8*)(src + i * 8);
            return;
        }
    }

#pragma unroll
    for (int mf = 0; mf < 4; mf++) {
#pragma unroll
        for (int nf = 0; nf < 4; nf++) {
            const int n_g = n0 + wn * 64 + nf * 16 + lr;
            const float bv = bias[n_g];
#pragma unroll
            for (int r = 0; r < 4; r++) {
                const int m_g = m0 + wm * 64 + mf * 16 + lg * 4 + r;
                const float v = acc[mf][nf][r] + bv;
                const size_t oidx = (size_t)m_g * N + n_g;
                if constexpr (MODE == 1) {
                    hres[oidx] = (f16)((float)hres[oidx] + v);
                } else if constexpr (MODE == 2) {
                    const float ge = 0.5f * v * (1.0f + erff(v * 0.70710678118654752f));
                    out16[oidx] = (f16)ge;
                } else if constexpr (MODE == 3) {
                    out16[oidx] = (f16)v;
                } else {
                    const int which = n_g / ND;
                    const int rem = n_g - which * ND;
                    const int hh = rem >> 6, dh = rem & 63;
                    const int bb2 = m_g >> 9, gg = m_g & (NG - 1);
                    if (which == 0)
                        Qo[((size_t)(bb2 * NH + hh) * NG + gg) * NDH + dh] = (f16)v;
                    else
                        Ko[((size_t)(bb2 * NH + hh) * NG + gg) * NDH + dh] = (f16)v;
                }
            }
        }
    }
}

// ---------------------------------------------------------------------------
// Fused GEMM (+residual +optional pos) + LayerNorm epilogue. BM=64, grid 512.
// OUT32=0: Hb=h_new(f16), Y=LN(h_new)(f16).  OUT32=1: LN(h_new)->f32 out only.
// ---------------------------------------------------------------------------
template<int ADDPOS, int OUT32>
__global__ __launch_bounds__(512)
void gemmln_kernel(const f16* __restrict__ A, const f16* __restrict__ Bt,
                   const float* __restrict__ bias, int K,
                   f16* __restrict__ hres, const f16* __restrict__ posadd,
                   const float* __restrict__ lw, const float* __restrict__ lb,
                   f16* __restrict__ Y, float* __restrict__ y32)
{
    __shared__ f16 sA[64 * 64];
    __shared__ f16 sB[384 * 64];
    __shared__ float part[2][64][2];
    const int tid = threadIdx.x;
    const int w = tid >> 6, lane = tid & 63;
    const int lr = lane & 15, lg = lane >> 4;
    const int vm = w >> 1, vn = w & 1;

    const int nwg = gridDim.x;
    const int chunk = nwg >> 3;
    const int m0 = ((blockIdx.x & 7) * chunk + (blockIdx.x >> 3)) * 64;

    f32x4 acc[12];
#pragma unroll
    for (int nf = 0; nf < 12; nf++)
        acc[nf] = (f32x4){0.f, 0.f, 0.f, 0.f};

    const int srowA = tid >> 3;          // 0..63
    const int scolB = (tid & 7) * 16;

    for (int k0 = 0; k0 < K; k0 += 64) {
        __syncthreads();
        {
            const int row = srowA;
            const int colB = scolB ^ ((row & 7) << 4);
            gload16((const char*)(A + (size_t)(m0 + row) * K + k0) + colB,
                    (char*)sA + row * 128 + scolB);
        }
#pragma unroll
        for (int i = 0; i < 6; i++) {
            const int row = i * 64 + srowA;
            const int colB = scolB ^ ((row & 7) << 4);
            gload16((const char*)(Bt + (size_t)row * K + k0) + colB,
                    (char*)sB + row * 128 + scolB);
        }
        __syncthreads();
#pragma unroll
        for (int kk = 0; kk < 64; kk += 32) {
            f16x8 af;
            {
                const int r = vm * 16 + lr;
                const int cb = ((kk + lg * 8) * 2) ^ ((r & 7) << 4);
                af = *(const f16x8*)((const char*)sA + r * 128 + cb);
            }
#pragma unroll
            for (int half = 0; half < 2; half++) {
                f16x8 bf[6];
#pragma unroll
                for (int j = 0; j < 6; j++) {
                    const int nf = half * 6 + j;
                    const int r = vn * 192 + nf * 16 + lr;
                    const int cb = ((kk + lg * 8) * 2) ^ ((r & 7) << 4);
                    bf[j] = *(const f16x8*)((const char*)sB + r * 128 + cb);
                }
#pragma unroll
                for (int j = 0; j < 6; j++)
                    acc[half * 6 + j] = __builtin_amdgcn_mfma_f32_16x16x32_f16(
                        af, bf[j], acc[half * 6 + j], 0, 0, 0);
            }
        }
    }

    f16v2 hn[12][2];
    float rs[4], rq[4];
#pragma unroll
    for (int r = 0; r < 4; r++) { rs[r] = 0.f; rq[r] = 0.f; }

#pragma unroll
    for (int nf = 0; nf < 12; nf++) {
        const int col = vn * 192 + nf * 16 + lr;
        const float bv = bias[col];
#pragma unroll
        for (int r = 0; r < 4; r++) {
            const int row_g = m0 + vm * 16 + lg * 4 + r;
            const size_t oidx = (size_t)row_g * ND + col;
            float hv = (float)hres[oidx] + acc[nf][r] + bv;
            if constexpr (ADDPOS) hv += (float)posadd[oidx];
            const f16 hf = (f16)hv;
            hn[nf][r >> 1][r & 1] = hf;
            const float hff = (float)hf;
            rs[r] += hff;
            rq[r] += hff * hff;
        }
    }
#pragma unroll
    for (int r = 0; r < 4; r++) {
#pragma unroll
        for (int off = 1; off < 16; off <<= 1) {
            rs[r] += __shfl_xor(rs[r], off);
            rq[r] += __shfl_xor(rq[r], off);
        }
    }
    if (lr == 0) {
#pragma unroll
        for (int r = 0; r < 4; r++) {
            const int rl = vm * 16 + lg * 4 + r;
            part[vn][rl][0] = rs[r];
            part[vn][rl][1] = rq[r];
        }
    }
    __syncthreads();

    float mus[4], rstds[4];
#pragma unroll
    for (int r = 0; r < 4; r++) {
        const int rl = vm * 16 + lg * 4 + r;
        const float s = part[0][rl][0] + part[1][rl][0];
        const float q = part[0][rl][1] + part[1][rl][1];
        const float mu = s * (1.f / ND);
        const float var = q * (1.f / ND) - mu * mu;
        mus[r] = mu;
        rstds[r] = rsqrtf(var + 1e-5f);
    }

#pragma unroll
    for (int nf = 0; nf < 12; nf++) {
        const int col = vn * 192 + nf * 16 + lr;
        const float wl = lw[col];
        const float bl = lb[col];
#pragma unroll
        for (int r = 0; r < 4; r++) {
            const int row_g = m0 + vm * 16 + lg * 4 + r;
            const size_t oidx = (size_t)row_g * ND + col;
            const f16 hf = hn[nf][r >> 1][r & 1];
            const float o = ((float)hf - mus[r]) * rstds[r] * wl + bl;
            if constexpr (OUT32) {
                y32[oidx] = o;
            } else {
                hres[oidx] = hf;
                Y[oidx] = (f16)o;
            }
        }
    }
}

// ---------------------------------------------------------------------------
// Flash attention, 128 q-rows per block, XCD-chunked grid + setprio (r15),
// K/V staged via gload16 + XOR-swizzle pair (GEMM-proven mechanism).
// ---------------------------------------------------------------------------
__global__ __launch_bounds__(256)
void attn_kernel(const f16* __restrict__ Q, const f16* __restrict__ Kt,
                 const f16* __restrict__ V, const unsigned char* __restrict__ flags,
                 f16* __restrict__ O)
{
    __shared__ f16 sQ[128][72];
    __shared__ f16 sK[64 * 64];
    __shared__ f16 sV[64 * 64];
    __shared__ f16 sP[4][16][72];
    const int tid = threadIdx.x;
    const int w = tid >> 6, lane = tid & 63;
    const int lr = lane & 15, lg = lane >> 4;

    const int nwg = gridDim.x;
    const int chunk = nwg >> 3;
    const int swz = (blockIdx.x & 7) * chunk + (blockIdx.x >> 3);
    const int qb = swz & 3;
    const int bh = swz >> 2;

    const int q0 = qb * 128;
    const int b = bh / NH, hh = bh - b * NH;
    const f16* Qg = Q + ((size_t)bh * NG + q0) * NDH;
    const f16* Kg = Kt + (size_t)bh * NG * NDH;
    const f16* Vg = V + (size_t)bh * NDH * NG;
    const unsigned char* fl = flags + b * NG;

#pragma unroll
    for (int i = 0; i < 4; i++) {
        const int c = tid + i * 256;
        const int r = c >> 3, cc = (c & 7) * 8;
        *(f16x8*)&sQ[r][cc] = *(const f16x8*)(Qg + r * NDH + cc);
    }
    __syncthreads();
    f16x8 aq[2][2];
#pragma unroll
    for (int hf = 0; hf < 2; hf++) {
        aq[hf][0] = *(const f16x8*)&sQ[hf * 64 + w * 16 + lr][lg * 8];
        aq[hf][1] = *(const f16x8*)&sQ[hf * 64 + w * 16 + lr][32 + lg * 8];
    }

    float m_run[2][4], l_run[2][4];
    f32x4 o[2][4];
#pragma unroll
    for (int hf = 0; hf < 2; hf++)
#pragma unroll
        for (int r = 0; r < 4; r++) {
            m_run[hf][r] = -INFINITY; l_run[hf][r] = 0.f;
            o[hf][r] = (f32x4){0.f, 0.f, 0.f, 0.f};
        }

    const int srow0 = tid >> 3;          // 0..31 (+32 per iter)
    const int scolB = (tid & 7) * 16;    // linear byte col

    const int ntile = 2 * qb + 2;
    for (int jt = 0; jt < ntile; jt++) {
        const int j0 = jt * 64;
        __syncthreads();
#pragma unroll
        for (int i = 0; i < 2; i++) {
            const int row = i * 32 + srow0;
            const int colB = scolB ^ ((row & 7) << 4);   // inverse-swizzled src
            gload16((const char*)(Kg + (size_t)(j0 + row) * NDH) + colB,
                    (char*)sK + row * 128 + scolB);
            gload16((const char*)(Vg + (size_t)row * NG + j0) + colB,
                    (char*)sV + row * 128 + scolB);
        }
        __syncthreads();

#pragma unroll
        for (int hf = 0; hf < 2; hf++) {
            if (jt >= ntile - 1 + hf) continue;
            f32x4 s[4];
#pragma unroll
            for (int nf = 0; nf < 4; nf++) s[nf] = (f32x4){0.f, 0.f, 0.f, 0.f};
            __builtin_amdgcn_s_setprio(1);
#pragma unroll
            for (int kf = 0; kf < 2; kf++) {
#pragma unroll
                for (int nf = 0; nf < 4; nf++) {
                    const int r = nf * 16 + lr;
                    const int cb = ((kf * 32 + lg * 8) * 2) ^ ((r & 7) << 4);
                    f16x8 bk = *(const f16x8*)((const char*)sK + r * 128 + cb);
                    s[nf] = __builtin_amdgcn_mfma_f32_16x16x32_f16(aq[hf][kf], bk, s[nf], 0, 0, 0);
                }
            }
            __builtin_amdgcn_s_setprio(0);
#pragma unroll
            for (int nf = 0; nf < 4; nf++) {
                const int j_g = j0 + nf * 16 + lr;
                const unsigned char f = fl[j_g];
#pragma unroll
                for (int r = 0; r < 4; r++) {
                    const int q_g = q0 + hf * 64 + w * 16 + lg * 4 + r;
                    const bool masked = (q_g < j_g) || (f & 2) || ((f & 1) && (j_g != q_g));
                    s[nf][r] = s[nf][r] * 0.125f + (masked ? -1e9f : 0.f);
                }
            }
#pragma unroll
            for (int r = 0; r < 4; r++) {
                float mx = fmaxf(fmaxf(s[0][r], s[1][r]), fmaxf(s[2][r], s[3][r]));
#pragma unroll
                for (int off = 1; off < 16; off <<= 1) mx = fmaxf(mx, __shfl_xor(mx, off));
                const float nm = fmaxf(m_run[hf][r], mx);
                const float sc = __expf(m_run[hf][r] - nm);
                m_run[hf][r] = nm;
                l_run[hf][r] *= sc;
#pragma unroll
                for (int nf = 0; nf < 4; nf++) o[hf][nf][r] *= sc;
                float ls = 0.f;
#pragma unroll
                for (int nf = 0; nf < 4; nf++) {
                    const float p = __expf(s[nf][r] - nm);
                    ls += p;
                    sP[w][lg * 4 + r][nf * 16 + lr] = (f16)p;
                }
                l_run[hf][r] += ls;
            }
            __builtin_amdgcn_s_setprio(1);
#pragma unroll
            for (int kf = 0; kf < 2; kf++) {
                f16x8 ap = *(const f16x8*)&sP[w][lr][kf * 32 + lg * 8];
#pragma unroll
                for (int nf = 0; nf < 4; nf++) {
                    const int r = nf * 16 + lr;
                    const int cb = ((kf * 32 + lg * 8) * 2) ^ ((r & 7) << 4);
                    f16x8 bv = *(const f16x8*)((const char*)sV + r * 128 + cb);
                    o[hf][nf] = __builtin_amdgcn_mfma_f32_16x16x32_f16(ap, bv, o[hf][nf], 0, 0, 0);
                }
            }
            __builtin_amdgcn_s_setprio(0);
        }
    }

#pragma unroll
    for (int hf = 0; hf < 2; hf++) {
        float inv[4];
#pragma unroll
        for (int r = 0; r < 4; r++) {
            float l = l_run[hf][r];
#pragma unroll
            for (int off = 1; off < 16; off <<= 1) l += __shfl_xor(l, off);
            inv[r] = 1.f / l;
        }
#pragma unroll
        for (int nf = 0; nf < 4; nf++) {
#pragma unroll
            for (int r = 0; r < 4; r++) {
                const int q_g = q0 + hf * 64 + w * 16 + lg * 4 + r;
                const int dh = nf * 16 + lr;
                O[((size_t)(b * NG + q_g)) * ND + hh * NDH + dh] = (f16)(o[hf][nf][r] * inv[r]);
            }
        }
    }
}

// ---------------------------------------------------------------------------
extern "C" void kernel_launch(void* const* d_in, const int* in_sizes, int n_in,
                              void* d_out, int out_size, void* d_ws, size_t ws_size,
                              hipStream_t stream)
{
    static const int exp_sizes[21] = {
        12582912, 98304, 32768,
        384, 128, 49152, 384,
        4608, 4608,
        5308416, 13824,
        1769472, 4608,
        4608, 4608,
        7077888, 18432,
        7077888, 4608,
        384, 384
    };
    if (n_in != 21 || out_size != 113278976) return;
    for (int i = 0; i < 21; i++) if (in_sizes[i] != exp_sizes[i]) return;

    const float* x    = (const float*)d_in[0];
    const float* cen  = (const float*)d_in[1];
    const float* noi  = (const float*)d_in[2];
    const float* pw1  = (const float*)d_in[3];
    const float* pb1  = (const float*)d_in[4];
    const float* pw2  = (const float*)d_in[5];
    const float* pb2  = (const float*)d_in[6];
    const float* ln1w = (const float*)d_in[7];
    const float* ln1b = (const float*)d_in[8];
    const float* qkvw = (const float*)d_in[9];
    const float* qkvb = (const float*)d_in[10];
    const float* projw= (const float*)d_in[11];
    const float* projb= (const float*)d_in[12];
    const float* ln2w = (const float*)d_in[13];
    const float* ln2b = (const float*)d_in[14];
    const float* fc1w = (const float*)d_in[15];
    const float* fc1b = (const float*)d_in[16];
    const float* fc2w = (const float*)d_in[17];
    const float* fc2b = (const float*)d_in[18];
    const float* nw   = (const float*)d_in[19];
    const float* nb   = (const float*)d_in[20];

    float* out0    = (float*)d_out;
    float* pad_out = out0 + BGD;
    float* R       = pad_out + BG;

    f16* WqkvT  = (f16*)(R + OFF_WQKV);
    f16* WprojT = (f16*)(R + OFF_WPROJ);
    f16* Wfc1T  = (f16*)(R + OFF_WFC1);
    f16* Wfc2T  = (f16*)(R + OFF_WFC2);
    int* nkm  = (int*)(R + OFF_NKM);
    int* Mmax = (int*)(R + OFF_MMAX);
    f16* POS   = (f16*)(R + OFF_POS);
    f16* HID   = (f16*)(R + OFF_HID);
    f16* Y     = (f16*)(R + OFF_Y);
    f16* Ybig  = (f16*)(R + OFF_YBIG);
    f16* Qb    = (f16*)(R + OFF_QB);
    f16* Kb    = (f16*)(R + OFF_KB);
    f16* Vt    = (f16*)(R + OFF_VT);
    f16* Ob    = (f16*)(R + OFF_OB);
    f16* W2T   = (f16*)(R + OFF_W2T);
    f16* Hb    = (f16*)(R + OFF_HB);

    const bool ws_flags = (ws_size >= 32768);
    unsigned char* flags = ws_flags ? (unsigned char*)d_ws
                                    : (unsigned char*)(R + OFF_FLAGS);

    dim3 tb(32, 8);
    transpose_kernel<<<dim3(36, 12, NL), tb, 0, stream>>>(qkvw, WqkvT, 384, 1152);
    transpose_kernel<<<dim3(12, 12, NL), tb, 0, stream>>>(projw, WprojT, 384, 384);
    transpose_kernel<<<dim3(48, 12, NL), tb, 0, stream>>>(fc1w, Wfc1T, 384, 1536);
    transpose_kernel<<<dim3(12, 48, NL), tb, 0, stream>>>(fc2w, Wfc2T, 1536, 384);
    transpose_kernel<<<dim3(12, 4, 1),  tb, 0, stream>>>(pw2, W2T, 128, 384);

    dmask_a<<<NB, 512, 0, stream>>>(cen, pad_out, nkm);
    dmask_m<<<1, 64, 0, stream>>>(nkm, Mmax);
    dmask_b<<<NB, 512, 0, stream>>>(cen, noi, nkm, Mmax, flags);
    dpos_a<<<BG * 128 / 256, 256, 0, stream>>>(cen, pw1, pb1, HID);
    gemm_kernel<3><<<768, 256, 0, stream>>>(HID, W2T, pb2, 128, 3,
                                            nullptr, POS,
                                            nullptr, nullptr, nullptr);
    pos_fix<<<NB, 384, 0, stream>>>(POS);
    h0_kernel<<<BGD / 256, 256, 0, stream>>>(x, POS, Hb);

    lnb_kernel<1><<<BG / 4, 256, 0, stream>>>(Hb, ln1w, ln1b, Y, nullptr);

    for (int l = 0; l < NL; l++) {
        gemm_kernel<0><<<2304, 256, 0, stream>>>(Y, WqkvT + (size_t)l * 442368,
                                                 qkvb + l * 1152, 384, 9,
                                                 nullptr, nullptr,
                                                 Qb, Kb, Vt);
        attn_kernel<<<4 * NB * NH, 256, 0, stream>>>(Qb, Kb, Vt, flags, Ob);
        gemmln_kernel<0, 0><<<512, 512, 0, stream>>>(Ob, WprojT + (size_t)l * 147456,
                                                     projb + l * ND, 384,
                                                     Hb, nullptr,
                                                     ln2w + l * ND, ln2b + l * ND,
                                                     Y, nullptr);
        gemm_kernel<2><<<3072, 256, 0, stream>>>(Y, Wfc1T + (size_t)l * 589824,
                                                 fc1b + l * 1536, 384, 12,
                                                 nullptr, Ybig,
                                                 nullptr, nullptr, nullptr);
        if (l < NL - 1) {
            gemmln_kernel<1, 0><<<512, 512, 0, stream>>>(Ybig, Wfc2T + (size_t)l * 589824,
                                                         fc2b + l * ND, 1536,
                                                         Hb, POS,
                                                         ln1w + (l + 1) * ND, ln1b + (l + 1) * ND,
                                                         Y, nullptr);
        } else {
            gemmln_kernel<0, 1><<<512, 512, 0, stream>>>(Ybig, Wfc2T + (size_t)l * 589824,
                                                         fc2b + l * ND, 1536,
                                                         Hb, nullptr,
                                                         nw, nb,
                                                         nullptr, out0);
        }
    }

    if (ws_flags) {
        mask_out_direct<<<BG, 512, 0, stream>>>(flags, R);
    } else {
        flags_rep_kernel<<<BG, 512, 0, stream>>>(flags, R);
        mask_out_kernel<<<BG, 512, 0, stream>>>(R);
    }
}

// Round 20
// 4289.241 us; speedup vs baseline: 1.0067x; 1.0067x over previous
//
#include <hip/hip_runtime.h>
#include <math.h>

typedef _Float16 f16;
typedef f16 f16x8 __attribute__((ext_vector_type(8)));
typedef f16 f16v2 __attribute__((ext_vector_type(2)));
typedef float f32x4 __attribute__((ext_vector_type(4)));

#define NB 64
#define NG 512
#define ND 384
#define NH 6
#define NL 12
#define NDH 64
#define BG (NB * NG)     // 32768
#define BGD (BG * ND)    // 12582912

// ---- scratch layout inside attn_mask region of d_out (float offsets) ----
#define OFF_WQKV   0          // f16[12*1152*384]
#define OFF_WPROJ  2654208
#define OFF_WFC1   3538944
#define OFF_WFC2   7077888
#define OFF_FLAGS  10616832
#define OFF_NKM    10625024
#define OFF_MMAX   10625216
#define OFF_POS    10625280   // f16[12,582,912] (6,291,456 floats)
#define OFF_HID    23208192   // f16[4,194,304]
#define OFF_Y      25305344   // f16[12,582,912]
#define OFF_YBIG   31596800   // f16[50,331,648]
#define OFF_QB     56762624   // f16[12,582,912]
#define OFF_KB     63054080
#define OFF_VT     69345536
#define OFF_OB     75636992
#define OFF_W2T    81928448   // f16[384*128]
#define OFF_HB     81953024   // f16[12,582,912] -> ends 88,244,480

// ---------------------------------------------------------------------------
// async global->LDS 16B
// ---------------------------------------------------------------------------
typedef __attribute__((address_space(3))) void lds_t;
typedef const __attribute__((address_space(1))) void gmem_t;
__device__ __forceinline__ void gload16(const void* g, void* l)
{
    __builtin_amdgcn_global_load_lds((gmem_t*)g, (lds_t*)l, 16, 0, 0);
}

// ---------------------------------------------------------------------------
// Weight transpose + fp32 -> fp16:  src [L][K][N] -> dst [L][N][K]
// ---------------------------------------------------------------------------
__global__ __launch_bounds__(256)
void transpose_kernel(const float* __restrict__ src, f16* __restrict__ dst,
                      int K, int N)
{
    __shared__ float tile[32][33];
    const int l = blockIdx.z;
    const float* S = src + (size_t)l * K * N;
    f16* D = dst + (size_t)l * K * N;
    const int n0 = blockIdx.x * 32, k0 = blockIdx.y * 32;
    const int tx = threadIdx.x, ty = threadIdx.y;
#pragma unroll
    for (int i = 0; i < 32; i += 8)
        tile[ty + i][tx] = S[(size_t)(k0 + ty + i) * N + n0 + tx];
    __syncthreads();
#pragma unroll
    for (int i = 0; i < 32; i += 8)
        D[(size_t)(n0 + ty + i) * K + k0 + tx] = (f16)tile[tx][ty + i];
}

// ---------------------------------------------------------------------------
// Positional MLP stage A (proven-dumb)
// ---------------------------------------------------------------------------
__global__ __launch_bounds__(256)
void dpos_a(const float* cen, const float* w1, const float* b1, f16* hid)
{
    const int idx = blockIdx.x * 256 + threadIdx.x;
    if (idx >= BG * 128) return;
    const int t = idx >> 7, k = idx & 127;
    const int g = t & (NG - 1);
    if (g == 0) { hid[idx] = (f16)0.f; return; }
    const float* c = cen + (size_t)(t - 1) * 3;
    const float hv = c[0] * w1[k] + c[1] * w1[128 + k] + c[2] * w1[256 + k] + b1[k];
    hid[idx] = (f16)(0.5f * hv * (1.0f + erff(hv * 0.70710678118654752f)));
}

__global__ __launch_bounds__(384)
void pos_fix(f16* pos)
{
    const int b = blockIdx.x;
    pos[((size_t)b * NG) * ND + threadIdx.x] = (f16)1.0f;
}

// ---------------------------------------------------------------------------
// Mask pipeline
// ---------------------------------------------------------------------------
__global__ __launch_bounds__(512)
void dmask_a(const float* cen, float* pad_out, int* nkm)
{
    const int b = blockIdx.x, j = threadIdx.x;
    const float* c = cen + ((size_t)b * NG + j) * 3;
    const bool pad = (c[0] == -1.f) && (c[1] == -1.f) && (c[2] == -1.f);
    pad_out[b * NG + j] = pad ? 1.f : 0.f;
    if (j == 0) {
        int cnt = 0;
        for (int i = 0; i < NG; i++) {
            const float* ci = cen + ((size_t)b * NG + i) * 3;
            cnt += (ci[0] == -1.f && ci[1] == -1.f && ci[2] == -1.f) ? 1 : 0;
        }
        const int n = NG - cnt;
        const int k = (int)((float)n * 0.1f);
        const int m = (int)((float)(n - k) * 0.6f);
        nkm[b * 3] = n; nkm[b * 3 + 1] = k; nkm[b * 3 + 2] = m;
    }
}

__global__ void dmask_m(const int* nkm, int* Mmax)
{
    if (threadIdx.x == 0 && blockIdx.x == 0) {
        int M = 0;
        for (int b = 0; b < NB; b++) M = max(M, nkm[b * 3 + 2]);
        *Mmax = M;
    }
}

// Stable-rank selection; noise staged in LDS (identical values & tie-break).
__global__ __launch_bounds__(512)
void dmask_b(const float* cen, const float* noi, const int* nkm,
             const int* Mmax, unsigned char* flags)
{
    __shared__ float u[NG];
    const int b = blockIdx.x, j = threadIdx.x;
    const int n = nkm[b * 3], k = nkm[b * 3 + 1], m = nkm[b * 3 + 2];
    const int M = *Mmax;
    const float nz = noi[b * NG + j];
    u[j] = nz;
    __syncthreads();
    const bool inreg = (j >= k) && (j < n);
    bool shuf = false;
    if (inreg) {
        int cnt = 0;
        for (int i = k; i < n; i++) {
            const float ui = u[i];
            cnt += (ui < nz) || (ui == nz && i < j);
        }
        shuf = cnt < m;
    }
    const float* c = cen + ((size_t)b * NG + j) * 3;
    const bool pad = (c[0] == -1.f) && (c[1] == -1.f) && (c[2] == -1.f);
    const bool tail = (j >= n) && (j < n + M - m);
    flags[b * NG + j] = (unsigned char)(((shuf | tail) ? 1 : 0) | (pad ? 2 : 0));
}

// ---------------------------------------------------------------------------
// attn_mask emission. Direct (flags in d_ws) + legacy fallback.
// ---------------------------------------------------------------------------
__global__ __launch_bounds__(512)
void mask_out_direct(const unsigned char* __restrict__ flags, float* __restrict__ mo)
{
    const int bq = blockIdx.x;
    const int b = bq >> 9, q = bq & (NG - 1);
    const int j = threadIdx.x;
    const unsigned char f = flags[b * NG + j];
    const float val = ((q < j) || ((f & 1) && (q != j))) ? 1.0f : 0.0f;
#pragma unroll
    for (int h = 0; h < NH; h++)
        mo[(((size_t)(b * NH + h) * NG + q) * NG) + j] = val;
}

__global__ __launch_bounds__(512)
void flags_rep_kernel(const unsigned char* flags, float* mo)
{
    const int bq = blockIdx.x;
    const int b = bq >> 9, q = bq & (NG - 1);
    const int j = threadIdx.x;
    mo[(((size_t)(b * NH) * NG + q) * NG) + j] = (float)flags[b * NG + j];
}

__global__ __launch_bounds__(512)
void mask_out_kernel(float* mo)
{
    const int bq = blockIdx.x;
    const int b = bq >> 9, q = bq & (NG - 1);
    const int j = threadIdx.x;
    const unsigned char f =
        (unsigned char)mo[(((size_t)(b * NH) * NG + q) * NG) + j];
    const float val = ((q < j) || ((f & 1) && (q != j))) ? 1.0f : 0.0f;
#pragma unroll
    for (int h = 0; h < NH; h++)
        mo[(((size_t)(b * NH + h) * NG + q) * NG) + j] = val;
}

// ---------------------------------------------------------------------------
// h0 init: shift-right + start token + pos-add (layer-0 fusion), f16 out
// ---------------------------------------------------------------------------
__global__ __launch_bounds__(256)
void h0_kernel(const float* x, const f16* pos, f16* h)
{
    const size_t i = (size_t)blockIdx.x * 256 + threadIdx.x;
    const int g = (int)((i / ND) & (NG - 1));
    const float xv = x[(g == 0) ? i : (i - ND)];
    const float base = (g == 0) ? 1.0f : xv;
    h[i] = (f16)(base + (float)pos[i]);
}

// ---------------------------------------------------------------------------
// LayerNorm standalone (pre-loop LN1 only). MODE 1: LN -> f16 Y.
// ---------------------------------------------------------------------------
template<int MODE>
__global__ __launch_bounds__(256)
void lnb_kernel(const f16* __restrict__ h,
                const float* __restrict__ w, const float* __restrict__ bb,
                f16* __restrict__ y16, float* __restrict__ y32)
{
    __shared__ float red[4][64];
    const int wid = threadIdx.x >> 6;
    const int lane = threadIdx.x & 63;
    const int t = blockIdx.x * 4 + wid;
    const size_t base = (size_t)t * ND + lane;
    float v[6];
    float s = 0.f;
#pragma unroll
    for (int i = 0; i < 6; i++) {
        const float xv = (float)h[base + i * 64];
        v[i] = xv; s += xv;
    }
    red[wid][lane] = s;
    __syncthreads();
    for (int st = 32; st > 0; st >>= 1) {
        if (lane < st) red[wid][lane] += red[wid][lane + st];
        __syncthreads();
    }
    const float mu = red[wid][0] * (1.f / ND);
    float vs = 0.f;
#pragma unroll
    for (int i = 0; i < 6; i++) { const float d = v[i] - mu; vs += d * d; }
    __syncthreads();
    red[wid][lane] = vs;
    __syncthreads();
    for (int st = 32; st > 0; st >>= 1) {
        if (lane < st) red[wid][lane] += red[wid][lane + st];
        __syncthreads();
    }
    const float rstd = rsqrtf(red[wid][0] * (1.f / ND) + 1e-5f);
#pragma unroll
    for (int i = 0; i < 6; i++) {
        const float o = (v[i] - mu) * rstd * w[lane + i * 64] + bb[lane + i * 64];
        if constexpr (MODE == 2) y32[base + i * 64] = o;
        else                     y16[base + i * 64] = (f16)o;
    }
}

// ---------------------------------------------------------------------------
// MFMA GEMM (proven green). MODE 0: QKV scatter (V tiles: LDS-bounce
// transposed coalesced write). MODE 1: hres(f16) += C. MODE 2: gelu->f16.
// MODE 3: plain C->f16.
// ---------------------------------------------------------------------------
template<int MODE>
__global__ __launch_bounds__(256)
void gemm_kernel(const f16* __restrict__ A, const f16* __restrict__ Bt,
                 const float* __restrict__ bias, int K, int NT,
                 f16* __restrict__ hres, f16* __restrict__ out16,
                 f16* __restrict__ Qo, f16* __restrict__ Ko, f16* __restrict__ Vo)
{
    __shared__ f16 sA[128 * 64];
    __shared__ f16 sB[128 * 64];
    const int tid = threadIdx.x;
    const int w = tid >> 6, lane = tid & 63;
    const int lr = lane & 15, lg = lane >> 4;
    const int wm = w >> 1, wn = w & 1;
    const int N = NT * 128;

    const int nwg = gridDim.x;
    const int chunk = nwg >> 3;
    const int flat = (blockIdx.x & 7) * chunk + (blockIdx.x >> 3);
    const int m0 = (flat / NT) * 128;
    const int n0 = (flat % NT) * 128;

    f32x4 acc[4][4];
#pragma unroll
    for (int mf = 0; mf < 4; mf++)
#pragma unroll
        for (int nf = 0; nf < 4; nf++)
            acc[mf][nf] = (f32x4){0.f, 0.f, 0.f, 0.f};

    const int srow0 = w * 8 + (lane >> 3);
    const int scolB = (lane & 7) * 16;

    for (int k0 = 0; k0 < K; k0 += 64) {
        __syncthreads();
#pragma unroll
        for (int i = 0; i < 4; i++) {
            const int row = i * 32 + srow0;
            const int colB = scolB ^ ((row & 7) << 4);
            const char* ga = (const char*)(A + (size_t)(m0 + row) * K + k0) + colB;
            const char* gb = (const char*)(Bt + (size_t)(n0 + row) * K + k0) + colB;
            gload16(ga, (char*)sA + row * 128 + scolB);
            gload16(gb, (char*)sB + row * 128 + scolB);
        }
        __syncthreads();
#pragma unroll
        for (int kk = 0; kk < 64; kk += 32) {
            f16x8 af[4], bf[4];
#pragma unroll
            for (int mf = 0; mf < 4; mf++) {
                const int r = wm * 64 + mf * 16 + lr;
                const int cb = ((kk + lg * 8) * 2) ^ ((r & 7) << 4);
                af[mf] = *(const f16x8*)((const char*)sA + r * 128 + cb);
            }
#pragma unroll
            for (int nf = 0; nf < 4; nf++) {
                const int r = wn * 64 + nf * 16 + lr;
                const int cb = ((kk + lg * 8) * 2) ^ ((r & 7) << 4);
                bf[nf] = *(const f16x8*)((const char*)sB + r * 128 + cb);
            }
#pragma unroll
            for (int mf = 0; mf < 4; mf++)
#pragma unroll
                for (int nf = 0; nf < 4; nf++)
                    acc[mf][nf] = __builtin_amdgcn_mfma_f32_16x16x32_f16(
                        af[mf], bf[nf], acc[mf][nf], 0, 0, 0);
        }
    }

    if constexpr (MODE == 0) {
        if (n0 >= 768) {
            // V tile: transpose through (now dead) sA/sB, then coalesced write.
            __syncthreads();
#pragma unroll
            for (int mf = 0; mf < 4; mf++) {
#pragma unroll
                for (int nf = 0; nf < 4; nf++) {
                    const int n_local = wn * 64 + nf * 16 + lr;
                    const float bv = bias[n0 + n_local];
                    f16* dst = (wn == 0 ? sA : sB)
                               + (n_local & 63) * 128 + wm * 64 + mf * 16 + lg * 4;
#pragma unroll
                    for (int r = 0; r < 4; r++)
                        dst[r] = (f16)(acc[mf][nf][r] + bv);
                }
            }
            __syncthreads();
            const int row = tid >> 1;
            const int seg = (tid & 1) * 64;
            const int rem = (n0 - 768) + row;
            const int hh = rem >> 6, dh = rem & 63;
            const int bb2 = m0 >> 9;
            const int gg0 = m0 & (NG - 1);
            const f16* src = (row < 64 ? sA : sB) + (row & 63) * 128 + seg;
            f16* dstg = Vo + ((size_t)(bb2 * NH + hh) * NDH + dh) * NG + gg0 + seg;
#pragma unroll
            for (int i = 0; i < 8; i++)
                *(f16x8*)(dstg + i * 8) = *(const f16x8*)(src + i * 8);
            return;
        }
    }

#pragma unroll
    for (int mf = 0; mf < 4; mf++) {
#pragma unroll
        for (int nf = 0; nf < 4; nf++) {
            const int n_g = n0 + wn * 64 + nf * 16 + lr;
            const float bv = bias[n_g];
#pragma unroll
            for (int r = 0; r < 4; r++) {
                const int m_g = m0 + wm * 64 + mf * 16 + lg * 4 + r;
                const float v = acc[mf][nf][r] + bv;
                const size_t oidx = (size_t)m_g * N + n_g;
                if constexpr (MODE == 1) {
                    hres[oidx] = (f16)((float)hres[oidx] + v);
                } else if constexpr (MODE == 2) {
                    const float ge = 0.5f * v * (1.0f + erff(v * 0.70710678118654752f));
                    out16[oidx] = (f16)ge;
                } else if constexpr (MODE == 3) {
                    out16[oidx] = (f16)v;
                } else {
                    const int which = n_g / ND;
                    const int rem = n_g - which * ND;
                    const int hh = rem >> 6, dh = rem & 63;
                    const int bb2 = m_g >> 9, gg = m_g & (NG - 1);
                    if (which == 0)
                        Qo[((size_t)(bb2 * NH + hh) * NG + gg) * NDH + dh] = (f16)v;
                    else
                        Ko[((size_t)(bb2 * NH + hh) * NG + gg) * NDH + dh] = (f16)v;
                }
            }
        }
    }
}

// ---------------------------------------------------------------------------
// Fused GEMM (+residual +optional pos) + LayerNorm epilogue. BM=64, grid 512.
// OUT32=0: Hb=h_new(f16), Y=LN(h_new)(f16).  OUT32=1: LN(h_new)->f32 out only.
// ---------------------------------------------------------------------------
template<int ADDPOS, int OUT32>
__global__ __launch_bounds__(512)
void gemmln_kernel(const f16* __restrict__ A, const f16* __restrict__ Bt,
                   const float* __restrict__ bias, int K,
                   f16* __restrict__ hres, const f16* __restrict__ posadd,
                   const float* __restrict__ lw, const float* __restrict__ lb,
                   f16* __restrict__ Y, float* __restrict__ y32)
{
    __shared__ f16 sA[64 * 64];
    __shared__ f16 sB[384 * 64];
    __shared__ float part[2][64][2];
    const int tid = threadIdx.x;
    const int w = tid >> 6, lane = tid & 63;
    const int lr = lane & 15, lg = lane >> 4;
    const int vm = w >> 1, vn = w & 1;

    const int nwg = gridDim.x;
    const int chunk = nwg >> 3;
    const int m0 = ((blockIdx.x & 7) * chunk + (blockIdx.x >> 3)) * 64;

    f32x4 acc[12];
#pragma unroll
    for (int nf = 0; nf < 12; nf++)
        acc[nf] = (f32x4){0.f, 0.f, 0.f, 0.f};

    const int srowA = tid >> 3;          // 0..63
    const int scolB = (tid & 7) * 16;

    for (int k0 = 0; k0 < K; k0 += 64) {
        __syncthreads();
        {
            const int row = srowA;
            const int colB = scolB ^ ((row & 7) << 4);
            gload16((const char*)(A + (size_t)(m0 + row) * K + k0) + colB,
                    (char*)sA + row * 128 + scolB);
        }
#pragma unroll
        for (int i = 0; i < 6; i++) {
            const int row = i * 64 + srowA;
            const int colB = scolB ^ ((row & 7) << 4);
            gload16((const char*)(Bt + (size_t)row * K + k0) + colB,
                    (char*)sB + row * 128 + scolB);
        }
        __syncthreads();
#pragma unroll
        for (int kk = 0; kk < 64; kk += 32) {
            f16x8 af;
            {
                const int r = vm * 16 + lr;
                const int cb = ((kk + lg * 8) * 2) ^ ((r & 7) << 4);
                af = *(const f16x8*)((const char*)sA + r * 128 + cb);
            }
#pragma unroll
            for (int half = 0; half < 2; half++) {
                f16x8 bf[6];
#pragma unroll
                for (int j = 0; j < 6; j++) {
                    const int nf = half * 6 + j;
                    const int r = vn * 192 + nf * 16 + lr;
                    const int cb = ((kk + lg * 8) * 2) ^ ((r & 7) << 4);
                    bf[j] = *(const f16x8*)((const char*)sB + r * 128 + cb);
                }
#pragma unroll
                for (int j = 0; j < 6; j++)
                    acc[half * 6 + j] = __builtin_amdgcn_mfma_f32_16x16x32_f16(
                        af, bf[j], acc[half * 6 + j], 0, 0, 0);
            }
        }
    }

    f16v2 hn[12][2];
    float rs[4], rq[4];
#pragma unroll
    for (int r = 0; r < 4; r++) { rs[r] = 0.f; rq[r] = 0.f; }

#pragma unroll
    for (int nf = 0; nf < 12; nf++) {
        const int col = vn * 192 + nf * 16 + lr;
        const float bv = bias[col];
#pragma unroll
        for (int r = 0; r < 4; r++) {
            const int row_g = m0 + vm * 16 + lg * 4 + r;
            const size_t oidx = (size_t)row_g * ND + col;
            float hv = (float)hres[oidx] + acc[nf][r] + bv;
            if constexpr (ADDPOS) hv += (float)posadd[oidx];
            const f16 hf = (f16)hv;
            hn[nf][r >> 1][r & 1] = hf;
            const float hff = (float)hf;
            rs[r] += hff;
            rq[r] += hff * hff;
        }
    }
#pragma unroll
    for (int r = 0; r < 4; r++) {
#pragma unroll
        for (int off = 1; off < 16; off <<= 1) {
            rs[r] += __shfl_xor(rs[r], off);
            rq[r] += __shfl_xor(rq[r], off);
        }
    }
    if (lr == 0) {
#pragma unroll
        for (int r = 0; r < 4; r++) {
            const int rl = vm * 16 + lg * 4 + r;
            part[vn][rl][0] = rs[r];
            part[vn][rl][1] = rq[r];
        }
    }
    __syncthreads();

    float mus[4], rstds[4];
#pragma unroll
    for (int r = 0; r < 4; r++) {
        const int rl = vm * 16 + lg * 4 + r;
        const float s = part[0][rl][0] + part[1][rl][0];
        const float q = part[0][rl][1] + part[1][rl][1];
        const float mu = s * (1.f / ND);
        const float var = q * (1.f / ND) - mu * mu;
        mus[r] = mu;
        rstds[r] = rsqrtf(var + 1e-5f);
    }

#pragma unroll
    for (int nf = 0; nf < 12; nf++) {
        const int col = vn * 192 + nf * 16 + lr;
        const float wl = lw[col];
        const float bl = lb[col];
#pragma unroll
        for (int r = 0; r < 4; r++) {
            const int row_g = m0 + vm * 16 + lg * 4 + r;
            const size_t oidx = (size_t)row_g * ND + col;
            const f16 hf = hn[nf][r >> 1][r & 1];
            const float o = ((float)hf - mus[r]) * rstds[r] * wl + bl;
            if constexpr (OUT32) {
                y32[oidx] = o;
            } else {
                hres[oidx] = hf;
                Y[oidx] = (f16)o;
            }
        }
    }
}

// ---------------------------------------------------------------------------
// Flash attention, 128 q-rows per block. Q fragments loaded DIRECTLY from
// global (each element used exactly once — staging was pure overhead);
// K/V staged via gload16 + XOR-swizzle pair (r19-proven). XCD grid + setprio.
// ---------------------------------------------------------------------------
__global__ __launch_bounds__(256)
void attn_kernel(const f16* __restrict__ Q, const f16* __restrict__ Kt,
                 const f16* __restrict__ V, const unsigned char* __restrict__ flags,
                 f16* __restrict__ O)
{
    __shared__ f16 sK[64 * 64];
    __shared__ f16 sV[64 * 64];
    __shared__ f16 sP[4][16][72];
    const int tid = threadIdx.x;
    const int w = tid >> 6, lane = tid & 63;
    const int lr = lane & 15, lg = lane >> 4;

    const int nwg = gridDim.x;
    const int chunk = nwg >> 3;
    const int swz = (blockIdx.x & 7) * chunk + (blockIdx.x >> 3);
    const int qb = swz & 3;
    const int bh = swz >> 2;

    const int q0 = qb * 128;
    const int b = bh / NH, hh = bh - b * NH;
    const f16* Qg = Q + ((size_t)bh * NG + q0) * NDH;
    const f16* Kg = Kt + (size_t)bh * NG * NDH;
    const f16* Vg = V + (size_t)bh * NDH * NG;
    const unsigned char* fl = flags + b * NG;

    // Q fragments direct from global (each element consumed exactly once)
    f16x8 aq[2][2];
#pragma unroll
    for (int hf = 0; hf < 2; hf++)
#pragma unroll
        for (int kf = 0; kf < 2; kf++)
            aq[hf][kf] = *(const f16x8*)(Qg + (size_t)(hf * 64 + w * 16 + lr) * NDH
                                         + kf * 32 + lg * 8);

    float m_run[2][4], l_run[2][4];
    f32x4 o[2][4];
#pragma unroll
    for (int hf = 0; hf < 2; hf++)
#pragma unroll
        for (int r = 0; r < 4; r++) {
            m_run[hf][r] = -INFINITY; l_run[hf][r] = 0.f;
            o[hf][r] = (f32x4){0.f, 0.f, 0.f, 0.f};
        }

    const int srow0 = tid >> 3;          // 0..31 (+32 per iter)
    const int scolB = (tid & 7) * 16;    // linear byte col

    const int ntile = 2 * qb + 2;
    for (int jt = 0; jt < ntile; jt++) {
        const int j0 = jt * 64;
        __syncthreads();
#pragma unroll
        for (int i = 0; i < 2; i++) {
            const int row = i * 32 + srow0;
            const int colB = scolB ^ ((row & 7) << 4);   // inverse-swizzled src
            gload16((const char*)(Kg + (size_t)(j0 + row) * NDH) + colB,
                    (char*)sK + row * 128 + scolB);
            gload16((const char*)(Vg + (size_t)row * NG + j0) + colB,
                    (char*)sV + row * 128 + scolB);
        }
        __syncthreads();

#pragma unroll
        for (int hf = 0; hf < 2; hf++) {
            if (jt >= ntile - 1 + hf) continue;
            f32x4 s[4];
#pragma unroll
            for (int nf = 0; nf < 4; nf++) s[nf] = (f32x4){0.f, 0.f, 0.f, 0.f};
            __builtin_amdgcn_s_setprio(1);
#pragma unroll
            for (int kf = 0; kf < 2; kf++) {
#pragma unroll
                for (int nf = 0; nf < 4; nf++) {
                    const int r = nf * 16 + lr;
                    const int cb = ((kf * 32 + lg * 8) * 2) ^ ((r & 7) << 4);
                    f16x8 bk = *(const f16x8*)((const char*)sK + r * 128 + cb);
                    s[nf] = __builtin_amdgcn_mfma_f32_16x16x32_f16(aq[hf][kf], bk, s[nf], 0, 0, 0);
                }
            }
            __builtin_amdgcn_s_setprio(0);
#pragma unroll
            for (int nf = 0; nf < 4; nf++) {
                const int j_g = j0 + nf * 16 + lr;
                const unsigned char f = fl[j_g];
#pragma unroll
                for (int r = 0; r < 4; r++) {
                    const int q_g = q0 + hf * 64 + w * 16 + lg * 4 + r;
                    const bool masked = (q_g < j_g) || (f & 2) || ((f & 1) && (j_g != q_g));
                    s[nf][r] = s[nf][r] * 0.125f + (masked ? -1e9f : 0.f);
                }
            }
#pragma unroll
            for (int r = 0; r < 4; r++) {
                float mx = fmaxf(fmaxf(s[0][r], s[1][r]), fmaxf(s[2][r], s[3][r]));
#pragma unroll
                for (int off = 1; off < 16; off <<= 1) mx = fmaxf(mx, __shfl_xor(mx, off));
                const float nm = fmaxf(m_run[hf][r], mx);
                const float sc = __expf(m_run[hf][r] - nm);
                m_run[hf][r] = nm;
                l_run[hf][r] *= sc;
#pragma unroll
                for (int nf = 0; nf < 4; nf++) o[hf][nf][r] *= sc;
                float ls = 0.f;
#pragma unroll
                for (int nf = 0; nf < 4; nf++) {
                    const float p = __expf(s[nf][r] - nm);
                    ls += p;
                    sP[w][lg * 4 + r][nf * 16 + lr] = (f16)p;
                }
                l_run[hf][r] += ls;
            }
            __builtin_amdgcn_s_setprio(1);
#pragma unroll
            for (int kf = 0; kf < 2; kf++) {
                f16x8 ap = *(const f16x8*)&sP[w][lr][kf * 32 + lg * 8];
#pragma unroll
                for (int nf = 0; nf < 4; nf++) {
                    const int r = nf * 16 + lr;
                    const int cb = ((kf * 32 + lg * 8) * 2) ^ ((r & 7) << 4);
                    f16x8 bv = *(const f16x8*)((const char*)sV + r * 128 + cb);
                    o[hf][nf] = __builtin_amdgcn_mfma_f32_16x16x32_f16(ap, bv, o[hf][nf], 0, 0, 0);
                }
            }
            __builtin_amdgcn_s_setprio(0);
        }
    }

#pragma unroll
    for (int hf = 0; hf < 2; hf++) {
        float inv[4];
#pragma unroll
        for (int r = 0; r < 4; r++) {
            float l = l_run[hf][r];
#pragma unroll
            for (int off = 1; off < 16; off <<= 1) l += __shfl_xor(l, off);
            inv[r] = 1.f / l;
        }
#pragma unroll
        for (int nf = 0; nf < 4; nf++) {
#pragma unroll
            for (int r = 0; r < 4; r++) {
                const int q_g = q0 + hf * 64 + w * 16 + lg * 4 + r;
                const int dh = nf * 16 + lr;
                O[((size_t)(b * NG + q_g)) * ND + hh * NDH + dh] = (f16)(o[hf][nf][r] * inv[r]);
            }
        }
    }
}

// ---------------------------------------------------------------------------
extern "C" void kernel_launch(void* const* d_in, const int* in_sizes, int n_in,
                              void* d_out, int out_size, void* d_ws, size_t ws_size,
                              hipStream_t stream)
{
    static const int exp_sizes[21] = {
        12582912, 98304, 32768,
        384, 128, 49152, 384,
        4608, 4608,
        5308416, 13824,
        1769472, 4608,
        4608, 4608,
        7077888, 18432,
        7077888, 4608,
        384, 384
    };
    if (n_in != 21 || out_size != 113278976) return;
    for (int i = 0; i < 21; i++) if (in_sizes[i] != exp_sizes[i]) return;

    const float* x    = (const float*)d_in[0];
    const float* cen  = (const float*)d_in[1];
    const float* noi  = (const float*)d_in[2];
    const float* pw1  = (const float*)d_in[3];
    const float* pb1  = (const float*)d_in[4];
    const float* pw2  = (const float*)d_in[5];
    const float* pb2  = (const float*)d_in[6];
    const float* ln1w = (const float*)d_in[7];
    const float* ln1b = (const float*)d_in[8];
    const float* qkvw = (const float*)d_in[9];
    const float* qkvb = (const float*)d_in[10];
    const float* projw= (const float*)d_in[11];
    const float* projb= (const float*)d_in[12];
    const float* ln2w = (const float*)d_in[13];
    const float* ln2b = (const float*)d_in[14];
    const float* fc1w = (const float*)d_in[15];
    const float* fc1b = (const float*)d_in[16];
    const float* fc2w = (const float*)d_in[17];
    const float* fc2b = (const float*)d_in[18];
    const float* nw   = (const float*)d_in[19];
    const float* nb   = (const float*)d_in[20];

    float* out0    = (float*)d_out;
    float* pad_out = out0 + BGD;
    float* R       = pad_out + BG;

    f16* WqkvT  = (f16*)(R + OFF_WQKV);
    f16* WprojT = (f16*)(R + OFF_WPROJ);
    f16* Wfc1T  = (f16*)(R + OFF_WFC1);
    f16* Wfc2T  = (f16*)(R + OFF_WFC2);
    int* nkm  = (int*)(R + OFF_NKM);
    int* Mmax = (int*)(R + OFF_MMAX);
    f16* POS   = (f16*)(R + OFF_POS);
    f16* HID   = (f16*)(R + OFF_HID);
    f16* Y     = (f16*)(R + OFF_Y);
    f16* Ybig  = (f16*)(R + OFF_YBIG);
    f16* Qb    = (f16*)(R + OFF_QB);
    f16* Kb    = (f16*)(R + OFF_KB);
    f16* Vt    = (f16*)(R + OFF_VT);
    f16* Ob    = (f16*)(R + OFF_OB);
    f16* W2T   = (f16*)(R + OFF_W2T);
    f16* Hb    = (f16*)(R + OFF_HB);

    const bool ws_flags = (ws_size >= 32768);
    unsigned char* flags = ws_flags ? (unsigned char*)d_ws
                                    : (unsigned char*)(R + OFF_FLAGS);

    dim3 tb(32, 8);
    transpose_kernel<<<dim3(36, 12, NL), tb, 0, stream>>>(qkvw, WqkvT, 384, 1152);
    transpose_kernel<<<dim3(12, 12, NL), tb, 0, stream>>>(projw, WprojT, 384, 384);
    transpose_kernel<<<dim3(48, 12, NL), tb, 0, stream>>>(fc1w, Wfc1T, 384, 1536);
    transpose_kernel<<<dim3(12, 48, NL), tb, 0, stream>>>(fc2w, Wfc2T, 1536, 384);
    transpose_kernel<<<dim3(12, 4, 1),  tb, 0, stream>>>(pw2, W2T, 128, 384);

    dmask_a<<<NB, 512, 0, stream>>>(cen, pad_out, nkm);
    dmask_m<<<1, 64, 0, stream>>>(nkm, Mmax);
    dmask_b<<<NB, 512, 0, stream>>>(cen, noi, nkm, Mmax, flags);
    dpos_a<<<BG * 128 / 256, 256, 0, stream>>>(cen, pw1, pb1, HID);
    gemm_kernel<3><<<768, 256, 0, stream>>>(HID, W2T, pb2, 128, 3,
                                            nullptr, POS,
                                            nullptr, nullptr, nullptr);
    pos_fix<<<NB, 384, 0, stream>>>(POS);
    h0_kernel<<<BGD / 256, 256, 0, stream>>>(x, POS, Hb);

    lnb_kernel<1><<<BG / 4, 256, 0, stream>>>(Hb, ln1w, ln1b, Y, nullptr);

    for (int l = 0; l < NL; l++) {
        gemm_kernel<0><<<2304, 256, 0, stream>>>(Y, WqkvT + (size_t)l * 442368,
                                                 qkvb + l * 1152, 384, 9,
                                                 nullptr, nullptr,
                                                 Qb, Kb, Vt);
        attn_kernel<<<4 * NB * NH, 256, 0, stream>>>(Qb, Kb, Vt, flags, Ob);
        gemmln_kernel<0, 0><<<512, 512, 0, stream>>>(Ob, WprojT + (size_t)l * 147456,
                                                     projb + l * ND, 384,
                                                     Hb, nullptr,
                                                     ln2w + l * ND, ln2b + l * ND,
                                                     Y, nullptr);
        gemm_kernel<2><<<3072, 256, 0, stream>>>(Y, Wfc1T + (size_t)l * 589824,
                                                 fc1b + l * 1536, 384, 12,
                                                 nullptr, Ybig,
                                                 nullptr, nullptr, nullptr);
        if (l < NL - 1) {
            gemmln_kernel<1, 0><<<512, 512, 0, stream>>>(Ybig, Wfc2T + (size_t)l * 589824,
                                                         fc2b + l * ND, 1536,
                                                         Hb, POS,
                                                         ln1w + (l + 1) * ND, ln1b + (l + 1) * ND,
                                                         Y, nullptr);
        } else {
            gemmln_kernel<0, 1><<<512, 512, 0, stream>>>(Ybig, Wfc2T + (size_t)l * 589824,
                                                         fc2b + l * ND, 1536,
                                                         Hb, nullptr,
                                                         nw, nb,
                                                         nullptr, out0);
        }
    }

    if (ws_flags) {
        mask_out_direct<<<BG, 512, 0, stream>>>(flags, R);
    } else {
        flags_rep_kernel<<<BG, 512, 0, stream>>>(flags, R);
        mask_out_kernel<<<BG, 512, 0, stream>>>(R);
    }
}